// Round 10
// baseline (150.680 us; speedup 1.0000x reference)
//
#include <hip/hip_runtime.h>
#include <math.h>

#define NQ 12
#define NL 6
#define TPB 64

// ---------------------------------------------------------------------------
// R17: R11 (correctness-verified: passed, absmax 0.0039) with the VGPR cap
// removed — __launch_bounds__(64,1) instead of (64,2).
//
// R11 post-mortem + R12/R13 A/B: launch_bounds arg2=2 caps the allocator at
// 128 VGPR == sizeof(v[64]) alone; everything else spilled (76 MB scratch
// writes, ~0.5 TB/s spill traffic). R11's 158us was spill, not the
// algorithm. With arg2=1: ~150-180 VGPR, no spill, 2 waves/SIMD resident,
// 8 waves/CU, grid 2048 1-wave blocks = all-resident, ZERO barriers.
//
// Structure (verified R11): single-wave blocks, XOR-diagonal storage.
// Storage A (layer entry): element (hi = label bits 6..11, lo = bits 0..5)
// at lane lo, reg d = hi^lo. Storage B (post-T1): lane hi, reg d.
//  h1: RY wires 5..0 = hi bits; hi_k = d_k^lane_k -> lane-signed s.
//  T1: one ds_bpermute per reg (lane L pulls lane L^d), in-place.
//  h2: RY wires 11..6 = lo bits, same lane-signed structure.
//  diag (l<5): merged D_om(l)*D_phi(l+1) at post-CNOT label gray12(lambda);
//      lane factor W[l][hi] (global), reg factor Z[l][lam6][lo] gathered
//      from 5KB LDS copy at lo = d^L.
//  fold+T2: odd-lane reg swap r<->r^63, then per-reg bpermute along
//      compile-time cycles of gray6^-1 (all steps data-independent).
//  Last layer: skip diag+fold; epilogue signs lane-only (wire0=L5,
//  wire1=L4^L5).
// ---------------------------------------------------------------------------

// ---- d_ws layout (float offsets) — identical to R10/R11 (prep verified) ----
#define WS_WA0 0        // 64 f2 : init lane factor e^{i(phi0_lane - pi/2*pop)}
#define WS_Z0  128      // 64 f2 : init hi factor   e^{i(phi0_hi  - pi/2*pop)}
#define WS_W   256      // 5*64 f2 : merged diag lane(=hi) factor
#define WS_Z   896      // 5*2*64 f2 : merged diag lo-table [l][lam6][lo]
#define WS_RYT 2176     // 72 float4 : (c,c,s,s) per (l,wire)

typedef float f2 __attribute__((ext_vector_type(2)));

static __device__ __forceinline__ f2 pk_mul(f2 a, f2 b) {
  f2 d; asm("v_pk_mul_f32 %0, %1, %2" : "=v"(d) : "v"(a), "v"(b)); return d;
}
static __device__ __forceinline__ f2 pk_fma(f2 a, f2 b, f2 c) {
  f2 d; asm("v_pk_fma_f32 %0, %1, %2, %3" : "=v"(d) : "v"(a), "v"(b), "v"(c)); return d;
}
// complex mul, both operands packed (re,im)
static __device__ __forceinline__ f2 cmulp(f2 a, f2 c) {
  f2 r1, d;
  asm("v_pk_mul_f32 %0, %1, %2 op_sel:[0,0] op_sel_hi:[0,1]"
      : "=v"(r1) : "v"(a), "v"(c));
  asm("v_pk_fma_f32 %0, %1, %2, %3 op_sel:[1,1,0] op_sel_hi:[1,0,1] neg_lo:[1,0,0]"
      : "=v"(d) : "v"(a), "v"(c), "v"(r1));
  return d;
}
// 64-lane gather: dst lane i <- src value on lane (addr>>2)
static __device__ __forceinline__ f2 bp2(int addr, f2 s) {
  f2 d;
  d.x = __int_as_float(__builtin_amdgcn_ds_bpermute(addr, __float_as_int(s.x)));
  d.y = __int_as_float(__builtin_amdgcn_ds_bpermute(addr, __float_as_int(s.y)));
  return d;
}

// RY with lane-signed s: u' = c*u + S*w ; w' = c*w - S*u  (S = +-s per lane)
template<int BIT>
static __device__ __forceinline__ void apply_ry64(f2 v[64], f2 cc, f2 SS) {
  #pragma unroll
  for (int j = 0; j < 64; ++j) {
    if (j & (1 << BIT)) continue;
    const int k = j | (1 << BIT);
    f2 a = v[j], b = v[k];
    f2 t1 = pk_mul(a, cc);
    f2 t2 = pk_mul(b, cc);
    v[j] = pk_fma(b, SS, t1);
    f2 nb;
    asm("v_pk_fma_f32 %0, %1, %2, %3 neg_lo:[1,0,0] neg_hi:[1,0,0]"
        : "=v"(nb) : "v"(a), "v"(SS), "v"(t2));
    v[k] = nb;
  }
}

// ---------------------------------------------------------------------------
// Prep kernel — verbatim R10/R11 (numerically verified by passing runs).
// ---------------------------------------------------------------------------
__global__ __launch_bounds__(256)
void qprep_kernel(const float* __restrict__ w, float* __restrict__ ws) {
  const int t = threadIdx.x;
  const float HPI = 1.57079632679489662f;

  if (t < 64) {              // WA0[u], u = label bits 0..5 <-> wires 11..6
    const int u = t;
    float f = 0.f;
    #pragma unroll
    for (int k = 0; k < 6; ++k) {
      float p = w[(0*NQ + (11-k))*3 + 0];
      f += ((u >> k) & 1) ? 0.5f*p : -0.5f*p;
    }
    f -= HPI * (float)__popc(u);
    float sv, cv; sincosf(f, &sv, &cv);
    ws[WS_WA0 + 2*u] = cv; ws[WS_WA0 + 2*u + 1] = sv;
  } else if (t < 128) {      // Z0[p], p = label bits 6..11 <-> wires 5..0
    const int p_ = t - 64;
    float f = 0.f;
    #pragma unroll
    for (int k = 0; k < 6; ++k) {
      float p = w[(0*NQ + (5-k))*3 + 0];
      f += ((p_ >> k) & 1) ? 0.5f*p : -0.5f*p;
    }
    f -= HPI * (float)__popc(p_);
    float sv, cv; sincosf(f, &sv, &cv);
    ws[WS_Z0 + 2*p_] = cv; ws[WS_Z0 + 2*p_ + 1] = sv;
  }

  // W[l][u], u = hi = label bits 6..11 (u_k <-> wire 5-k):
  //   om(l) over u_k; phi(l+1) over gray bits g_{6+k} = u_k^u_{k+1} (g11=u5)
  for (int idx = t; idx < 5*64; idx += 256) {
    const int l = idx >> 6, u = idx & 63;
    float f = 0.f;
    #pragma unroll
    for (int k = 0; k < 6; ++k) {
      float om = w[(l*NQ + (5-k))*3 + 2];
      f += ((u >> k) & 1) ? 0.5f*om : -0.5f*om;
    }
    const int gu = u ^ (u >> 1);
    #pragma unroll
    for (int k = 0; k < 6; ++k) {
      float ph = w[((l+1)*NQ + (5-k))*3 + 0];
      f += ((gu >> k) & 1) ? 0.5f*ph : -0.5f*ph;
    }
    float sv, cv; sincosf(f, &sv, &cv);
    ws[WS_W + 2*idx] = cv; ws[WS_W + 2*idx + 1] = sv;
  }

  // Z[l][h][p], p = lo = label bits 0..5 (p_k <-> wire 11-k), h = lam6:
  //   om(l) over p_k; phi(l+1) over g_k = p_k^p_{k+1} (k<5), g5 = p5^h
  for (int idx = t; idx < 5*2*64; idx += 256) {
    const int l = idx >> 7, h = (idx >> 6) & 1, p_ = idx & 63;
    float f = 0.f;
    #pragma unroll
    for (int k = 0; k < 6; ++k) {
      float om = w[(l*NQ + (11-k))*3 + 2];
      f += ((p_ >> k) & 1) ? 0.5f*om : -0.5f*om;
    }
    const int gp = (p_ ^ (p_ >> 1)) ^ (h << 5);
    #pragma unroll
    for (int k = 0; k < 6; ++k) {
      float ph = w[((l+1)*NQ + (11-k))*3 + 0];
      f += ((gp >> k) & 1) ? 0.5f*ph : -0.5f*ph;
    }
    float sv, cv; sincosf(f, &sv, &cv);
    ws[WS_Z + 2*idx] = cv; ws[WS_Z + 2*idx + 1] = sv;
  }

  if (t < NL*NQ) {           // ryt: (c,c,s,s) of theta/2 per (l,wire)
    float sv, cv; sincosf(0.5f*w[t*3 + 1], &sv, &cv);
    ((float4*)(ws + WS_RYT))[t] = make_float4(cv, cv, sv, sv);
  }
}

// fold cycle-walk macros: new[e] <- swapped[g6inv(e)], pulled from lane
// g6inv(e)^g6inv(L); addr = vgi ^ (SRC<<2) since SRC = g6inv(DST).
// All steps read pre-fold regs exactly once before overwrite -> independent.
#define STEP(DST, SRC) v[DST] = bp2(vgi ^ ((SRC) << 2), v[SRC]);
#define CYC2(A,B) { f2 t_ = v[A]; STEP(A,B); v[B] = bp2(vgi ^ ((A) << 2), t_); }
#define CYC4(A,B,C,D) { f2 t_ = v[A]; STEP(A,B); STEP(B,C); STEP(C,D); \
                        v[D] = bp2(vgi ^ ((A) << 2), t_); }
#define CYC8(A,B,C,D,E,F,G,H) { f2 t_ = v[A]; STEP(A,B); STEP(B,C); STEP(C,D); \
                        STEP(D,E); STEP(E,F); STEP(F,G); STEP(G,H); \
                        v[H] = bp2(vgi ^ ((A) << 2), t_); }

// ---------------------------------------------------------------------------
// Main kernel: 1 wave per block, XOR-diag storage, 64 amps per lane.
// __launch_bounds__(TPB, 1): arg2>=2 caps VGPR at 128 == v[64] alone and
// spills everything else (R11/R12 post-mortem; R13 A/B confirmed).
// ---------------------------------------------------------------------------
__global__ __launch_bounds__(TPB, 1)
void qsim12_kernel(const float* __restrict__ x, const float* __restrict__ ws,
                   float* __restrict__ out) {
  __shared__ __align__(16) float zt[5*2*64*2];   // 5120 B Z-table copy
  const int L = threadIdx.x;
  const int b = blockIdx.x;

  // copy Z tables to LDS (coalesced; single wave -> lgkmcnt ordering only)
  #pragma unroll
  for (int i = 0; i < 10; ++i)
    ((f2*)zt)[i*64 + L] = *(const f2*)(ws + WS_Z + 2*(i*64 + L));

  // x cos/sin: lanes 0..11 compute, readlane broadcast
  float csx[NQ], csy[NQ];
  {
    float xv = (L < NQ) ? x[b*NQ + L] : 0.f;
    float sv, cv; sincosf(0.5f*xv, &sv, &cv);
    #pragma unroll
    for (int q = 0; q < NQ; ++q) {
      csx[q] = __int_as_float(__builtin_amdgcn_readlane(__float_as_int(cv), q));
      csy[q] = __int_as_float(__builtin_amdgcn_readlane(__float_as_int(sv), q));
    }
  }

  f2 v[64];
  const int lb = L << 2;

  // ---- Init (A-storage): v[d]@lane L = element(hi=d^L, lo=L)
  //   = rl(L)*WA0(L) * m(hi)*Z0(hi), hi-part pulled by XOR shuffle.
  {
    float rl = 1.f;
    #pragma unroll
    for (int k = 0; k < 6; ++k)
      rl *= ((L >> k) & 1) ? csy[11-k] : csx[11-k];
    float mh = 1.f;
    #pragma unroll
    for (int k = 0; k < 6; ++k)
      mh *= ((L >> k) & 1) ? csy[5-k] : csx[5-k];
    const float2 z0 = *(const float2*)(ws + WS_Z0 + 2*L);
    const float2 w0 = *(const float2*)(ws + WS_WA0 + 2*L);
    const f2 zm = (f2){z0.x*mh, z0.y*mh};     // lane L holds hi=L factor
    const f2 a0 = (f2){w0.x*rl, w0.y*rl};
    #pragma unroll
    for (int d = 0; d < 64; ++d)
      v[d] = cmulp(a0, bp2(lb ^ (d << 2), zm));
  }

  // g6inv(L) byte addr (suffix-xor) + parity for the fold
  int gi = L; gi ^= gi >> 1; gi ^= gi >> 2; gi ^= gi >> 4;
  const int vgi = gi << 2;
  const bool oddl = (L & 1) != 0;

  #define RYS(BIT, WQ) { \
    const float4 r_ = *(const float4*)(ws + WS_RYT + 4*(l*NQ + (WQ)));   \
    const float S_ = ((L >> (BIT)) & 1) ? r_.z : -r_.z;                  \
    apply_ry64<BIT>(v, (f2){r_.x, r_.x}, (f2){S_, S_}); }

  #pragma unroll 1
  for (int l = 0; l < NL; ++l) {
    // h1: wires 5..0 (hi bits 0..5)
    RYS(0,5) RYS(1,4) RYS(2,3) RYS(3,2) RYS(4,1) RYS(5,0)

    // T1: A->B, per-reg XOR-lane shuffle (in-place safe)
    #pragma unroll
    for (int d = 0; d < 64; ++d)
      v[d] = bp2(lb ^ (d << 2), v[d]);

    // h2: wires 11..6 (lo bits 0..5)
    RYS(0,11) RYS(1,10) RYS(2,9) RYS(3,8) RYS(4,7) RYS(5,6)

    if (l < NL-1) {
      // merged diag at post-CNOT label gray12(lambda): lane(=hi) factor W,
      // lo-table Z gathered at index lo = d^L with lam6 = lane bit 0 select
      const float2 wv = *(const float2*)(ws + WS_W + (l*64 + L)*2);
      const f2 W = (f2){wv.x, wv.y};
      const int zb = ((l*2 + (L & 1)) << 9) + (L << 3);   // byte base
      #pragma unroll
      for (int d = 0; d < 64; ++d) {
        const f2 z = *(const f2*)((const char*)zt + (zb ^ (d << 3)));
        v[d] = cmulp(cmulp(v[d], z), W);
      }

      // fold step (a): odd lanes (lam_hi odd) swap regs r <-> r^63
      #pragma unroll
      for (int r = 0; r < 32; ++r) {
        const f2 a = v[r], c = v[63 - r];
        v[r]      = oddl ? c : a;
        v[63 - r] = oddl ? a : c;
      }
      // fold step (b): per-reg bpermute along g6inv cycles (in-place)
      STEP(0,0) STEP(1,1)
      CYC2(2,3)
      CYC4(4,7,5,6)
      CYC4(8,15,10,12)
      CYC4(9,14,11,13)
      CYC8(16,31,21,25,17,30,20,24)
      CYC8(18,28,23,26,19,29,22,27)
      CYC8(32,63,42,51,34,60,40,48)
      CYC8(33,62,43,50,35,61,41,49)
      CYC8(36,56,47,53,38,59,45,54)
      CYC8(37,57,46,52,39,58,44,55)
    }
  }

  // ---- Epilogue (B-storage: lane = hi = label bits 6..11).
  // post-CNOT wire0 = lam11 = L5; wire1 = lam10^lam11 = L4^L5.
  float ssum = 0.f;
  #pragma unroll
  for (int p = 0; p < 64; ++p)
    ssum += v[p].x*v[p].x + v[p].y*v[p].y;
  float s0 = ((L >> 5) & 1) ? -ssum : ssum;
  float s1 = (((L >> 4) ^ (L >> 5)) & 1) ? -ssum : ssum;
  #pragma unroll
  for (int off = 32; off >= 1; off >>= 1) {
    s0 += __shfl_down(s0, off);
    s1 += __shfl_down(s1, off);
  }
  if (L == 0) { out[b*2 + 0] = s0; out[b*2 + 1] = s1; }
}

extern "C" void kernel_launch(void* const* d_in, const int* in_sizes, int n_in,
                              void* d_out, int out_size, void* d_ws, size_t ws_size,
                              hipStream_t stream) {
  const float* x = (const float*)d_in[0];      // (B, 12) f32
  const float* w = (const float*)d_in[1];      // (6, 12, 3) f32
  float* out = (float*)d_out;                  // (B, 2) f32
  float* ws = (float*)d_ws;                    // needs >= 9856 B
  int B = in_sizes[0] / NQ;
  qprep_kernel<<<1, 256, 0, stream>>>(w, ws);
  qsim12_kernel<<<B, TPB, 0, stream>>>(x, ws, out);
}

// Round 12
// 125.383 us; speedup vs baseline: 1.2018x; 1.2018x over previous
//
#include <hip/hip_runtime.h>
#include <math.h>

#define NQ 12
#define DIM 4096
#define NL 6
#define TPB 256

// ---------------------------------------------------------------------------
// R19: exact restoration of R15 (verified round 8: passed, absmax 0.0039,
// main 79us, bench 125us).
//
// R18 post-mortem: replacing the post-pass-A block barrier with a wave-local
// s_waitcnt lgkmcnt(0) produced NONDETERMINISTIC output (harness tripwire:
// launch_once diverged from timed graph). Static analysis says the A->B
// exchange is wave-private (A stores row t; B reads rows 16*(t>>4)..+15;
// 16-groups never straddle waves; lanes are lockstep) — but the empirical
// verdict overrules: either compiler motion across the volatile asm
// (rule-18 hazard family) or an LDS write-visibility subtlety. Barrier
// weakening on this structure is closed. All three block barriers restored.
//
// Kernel content (verified): R9 3-pass structure + merged boundary diagonals
// (D_om(l)*D_phi(l+1) applied once at pass C, evaluated at post-CNOT gray
// label) + lifting-scheme RY butterflies (3 pk-FMA/pair):
//   R = [[1,w],[0,1]]·[[1,0],[s,1]]·[[1,w],[0,1]],
//   s = sin(th/2), w = -tan(th/4)   (half-angle rotation coefficients).
// ---------------------------------------------------------------------------

// ---- d_ws table layout (float offsets) ----
#define WS_WA0 0      // 256 f2  : layer-0 D_phi thread factor e^{i fA0(t)}
#define WS_W   512    // 5*256 f2: merged D_om(l)*D_phi(l+1) thread factor
#define WS_ZA0 3072   // 16 f2   : layer-0 D_phi group factor (label bits 0-3)
#define WS_ZM  3104   // 5*2*16 f2: merged group factor, idx ((l*2+t7)*16+j)
#define WS_RYT 3424   // 72 float4: (w,w,s,s) per (l,wire)  [lifting coeffs]
#define WS_FLOATS 3712  // 14848 bytes total

typedef float f2 __attribute__((ext_vector_type(2)));

__device__ __forceinline__ f2 pk_mul(f2 a, f2 b) {
  f2 d; asm("v_pk_mul_f32 %0, %1, %2" : "=v"(d) : "v"(a), "v"(b)); return d;
}
__device__ __forceinline__ f2 pk_fma(f2 a, f2 b, f2 c) {
  f2 d; asm("v_pk_fma_f32 %0, %1, %2, %3" : "=v"(d) : "v"(a), "v"(b), "v"(c)); return d;
}
// complex mul, both operands packed (re,im)
__device__ __forceinline__ f2 cmulp(f2 a, f2 c) {
  f2 r1, d;
  asm("v_pk_mul_f32 %0, %1, %2 op_sel:[0,0] op_sel_hi:[0,1]"
      : "=v"(r1) : "v"(a), "v"(c));
  asm("v_pk_fma_f32 %0, %1, %2, %3 op_sel:[1,1,0] op_sel_hi:[1,0,1] neg_lo:[1,0,0]"
      : "=v"(d) : "v"(a), "v"(c), "v"(r1));
  return d;
}

// Lifting RY pair update: a += w*b; b += s*a; a += w*b
// == a' = c*a - s*b ; b' = s*a + c*b   (3 pk-FMA vs 4; R15-verified)
template<int BIT>
__device__ __forceinline__ void apply_ry16(f2 v[16], f2 ww, f2 ss) {
  #pragma unroll
  for (int j = 0; j < 16; ++j) {
    if (j & (1 << BIT)) continue;
    const int k = j | (1 << BIT);
    f2 a = v[j], b = v[k];
    a = pk_fma(b, ww, a);
    b = pk_fma(a, ss, b);
    a = pk_fma(b, ww, a);
    v[j] = a; v[k] = b;
  }
}

// ---------------------------------------------------------------------------
// Prep kernel: 1 block x 256 threads, fills d_ws from w. Runs once, ~2 us.
// w layout: w[(l*NQ + q)*3 + c], c: 0=phi, 1=theta, 2=omega.
// ---------------------------------------------------------------------------
__global__ __launch_bounds__(256)
void qprep_kernel(const float* __restrict__ w, float* __restrict__ ws) {
  const int t = threadIdx.x;

  // WA0[t] = e^{i * sum_k (t_k ? + : -) phi(0, 7-k)/2}   (label bit 4+k)
  {
    float f = 0.f;
    #pragma unroll
    for (int k = 0; k < 8; ++k) {
      float p = w[(0*NQ + 7 - k)*3 + 0];
      f += ((t >> k) & 1) ? 0.5f*p : -0.5f*p;
    }
    float sv, cv; sincosf(f, &sv, &cv);
    ws[WS_WA0 + 2*t] = cv; ws[WS_WA0 + 2*t + 1] = sv;
  }

  // W[l][t], l=0..4: omega(l) over t_k (label bit k <-> wire 11-k)
  //                + phi(l+1) over gray bits g_k = t_k^t_{k+1}, k=0..6
  #pragma unroll 1
  for (int l = 0; l < NL-1; ++l) {
    float f = 0.f;
    const int gt = t ^ (t >> 1);
    #pragma unroll
    for (int k = 0; k < 8; ++k) {
      float om = w[(l*NQ + 11 - k)*3 + 2];
      f += ((t >> k) & 1) ? 0.5f*om : -0.5f*om;
    }
    #pragma unroll
    for (int k = 0; k < 7; ++k) {
      float ph = w[((l+1)*NQ + 11 - k)*3 + 0];
      f += ((gt >> k) & 1) ? 0.5f*ph : -0.5f*ph;
    }
    float sv, cv; sincosf(f, &sv, &cv);
    ws[WS_W + (l*256 + t)*2] = cv; ws[WS_W + (l*256 + t)*2 + 1] = sv;
  }

  // zA0[j], j<16: phi(0) over j_m (label bit m <-> wire 11-m)
  if (t < 16) {
    float f = 0.f;
    #pragma unroll
    for (int m = 0; m < 4; ++m) {
      float p = w[(0*NQ + 11 - m)*3 + 0];
      f += ((t >> m) & 1) ? 0.5f*p : -0.5f*p;
    }
    float sv, cv; sincosf(f, &sv, &cv);
    ws[WS_ZA0 + 2*t] = cv; ws[WS_ZA0 + 2*t + 1] = sv;
  }

  // zM[l][h][j], idx = (l*2+h)*16+j, t<160:
  //   omega(l):  wires 3-m by j_m (label bits 8-11)
  //   phi(l+1):  g7 = h^j0 -> wire4; g8..g11 = (j^(j>>1)) bits 0..3 -> wires 3..0
  if (t < 160) {
    const int l = t >> 5, h = (t >> 4) & 1, j = t & 15;
    float f = 0.f;
    #pragma unroll
    for (int m = 0; m < 4; ++m) {
      float om = w[(l*NQ + 3 - m)*3 + 2];
      f += ((j >> m) & 1) ? 0.5f*om : -0.5f*om;
    }
    {
      float p4 = w[((l+1)*NQ + 4)*3 + 0];
      f += (h ^ (j & 1)) ? 0.5f*p4 : -0.5f*p4;
    }
    const int gj = j ^ (j >> 1);
    #pragma unroll
    for (int m = 0; m < 4; ++m) {
      float ph = w[((l+1)*NQ + 3 - m)*3 + 0];
      f += ((gj >> m) & 1) ? 0.5f*ph : -0.5f*ph;
    }
    float sv, cv; sincosf(f, &sv, &cv);
    ws[WS_ZM + 2*t] = cv; ws[WS_ZM + 2*t + 1] = sv;
  }

  // ryt[g], g<72: lifting coeffs of the HALF-ANGLE rotation:
  //   butterfly rotation angle is th/2  ->  s = sin(th/2), w = -tan(th/4)
  if (t < NL*NQ) {
    float th = w[t*3 + 1];
    float sv = sinf(0.5f*th);
    float wv = -tanf(0.25f*th);
    ((float4*)(ws + WS_RYT))[t] = make_float4(wv, wv, sv, sv);
  }
}

// ---------------------------------------------------------------------------
// Main kernel. LDS = 32768 B exactly -> 5 blocks/CU. (R15-verbatim body.)
// ---------------------------------------------------------------------------
__global__ __launch_bounds__(TPB, 5)
void qsim12_kernel(const float* __restrict__ x, const float* __restrict__ ws,
                   float* __restrict__ out) {
  __shared__ __align__(16) float st[2*DIM];   // 32 KB state (swizzled) ONLY

  const int t = threadIdx.x;
  const int b = blockIdx.x;
  char* stb = (char*)st;

  // x cos/sin: lanes 0-11 of each wave compute, readlane-broadcast to SGPRs.
  float csx[NQ], csy[NQ];
  {
    const int q = t & 63;
    float xv = (q < NQ) ? x[b*NQ + q] : 0.f;
    float sv, cv; sincosf(0.5f*xv, &sv, &cv);
    #pragma unroll
    for (int qq = 0; qq < NQ; ++qq) {
      csx[qq] = __int_as_float(__builtin_amdgcn_readlane(__float_as_int(cv), qq));
      csy[qq] = __int_as_float(__builtin_amdgcn_readlane(__float_as_int(sv), qq));
    }
  }

  // Precomputed byte-address bases (verified R5/R7 — unchanged).
  int baseA[8], baseB[8];
  #pragma unroll
  for (int m = 0; m < 8; ++m) {
    baseA[m] = (t << 7) + (((2*m) ^ (t & 14)) << 3);                 // phys14, A b128
    baseB[m] = ((t >> 4) << 11) + ((((t & 15) ^ (2*m))) << 3);       // + j*128
  }
  const int baseC = ((t >> 4) << 7) + ((((t & 15) ^ ((t >> 4) & 15))) << 3);  // + j*2048
  const int G = t ^ (t >> 1);
  int baseS[2];
  #pragma unroll
  for (int par = 0; par < 2; ++par) {
    const int k8 = par << 3;
    baseS[par] = ((((G >> 4) & 15) ^ k8) << 7)
               + ((((G & 15) ^ ((G >> 4) & 14) ^ k8)) << 3);
  }

  f2 v[16];

  // ---- Init: amp(label) = prod_w (bit? sin:cos) * (-i)^popcount(label).
  {
    float rhi = 1.f;
    #pragma unroll
    for (int k = 0; k < 8; ++k)
      rhi *= ((t >> k) & 1) ? csy[7-k] : csx[7-k];
    const int popt = __popc(t);
    #pragma unroll
    for (int j = 0; j < 16; ++j) {
      float r = rhi;
      #pragma unroll
      for (int m = 0; m < 4; ++m)
        r *= ((j >> m) & 1) ? csy[11-m] : csx[11-m];
      const int pj = (popt + __popc(j)) & 3;
      if      (pj == 0) v[j] = (f2){ r, 0.f};
      else if (pj == 1) v[j] = (f2){0.f, -r};
      else if (pj == 2) v[j] = (f2){-r, 0.f};
      else              v[j] = (f2){0.f,  r};
    }
  }

  #define RY(BIT, WQ)                                                     \
    { const float4 r = *(const float4*)(ws + WS_RYT + 4*(l*NQ + (WQ)));   \
      apply_ry16<BIT>(v, (f2){r.x, r.y}, (f2){r.z, r.w}); }

  #pragma unroll 1
  for (int l = 0; l < NL; ++l) {
    // ---- pass A: wires 11..8 (label bits 0..3)
    if (l > 0) {
      // diag for this boundary was already applied (merged) at pass C of l-1
      #pragma unroll
      for (int m = 0; m < 8; ++m) {
        float4 q4 = *(const float4*)(stb + baseA[m]);
        v[2*m]   = (f2){q4.x, q4.y};
        v[2*m+1] = (f2){q4.z, q4.w};
      }
    } else {
      // D_phi(0): group (label bits 0-3) table x thread factor
      const float2 wv = *(const float2*)(ws + WS_WA0 + 2*t);
      const f2 wA0 = (f2){wv.x, wv.y};
      #pragma unroll
      for (int j = 0; j < 16; ++j) {
        const float2 zv = *(const float2*)(ws + WS_ZA0 + 2*j);
        v[j] = cmulp(cmulp(v[j], (f2){zv.x, zv.y}), wA0);
      }
    }
    RY(0,11) RY(1,10) RY(2,9) RY(3,8)
    #pragma unroll
    for (int m = 0; m < 8; ++m)
      *(float4*)(stb + baseA[m]) =
          make_float4(v[2*m].x, v[2*m].y, v[2*m+1].x, v[2*m+1].y);
    __syncthreads();

    // ---- pass B: wires 7..4 (label bits 4..7); load phys14, store phys15
    #pragma unroll
    for (int m = 0; m < 8; ++m) {
      v[2*m]   = *(const f2*)(stb + baseB[m] + (2*m)*128);
      v[2*m+1] = *(const f2*)(stb + baseB[m] + (2*m+1)*128);
    }
    RY(0,7) RY(1,6) RY(2,5) RY(3,4)
    #pragma unroll
    for (int m = 0; m < 8; ++m) {
      *(f2*)(stb + baseB[m] + (2*m)*128)         = v[2*m];
      *(f2*)(stb + (baseB[m] ^ 8) + (2*m+1)*128) = v[2*m+1];
    }
    __syncthreads();

    // ---- pass C: wires 3..0 (label bits 8..11); load phys15
    #pragma unroll
    for (int j = 0; j < 16; ++j)
      v[j] = *(const f2*)(stb + baseC + j*2048);
    RY(0,3) RY(1,2) RY(2,1) RY(3,0)
    if (l < NL-1) {
      // merged diag: D_om(l) * D_phi(l+1) evaluated at post-CNOT label
      // gray(lambda). Group part zM[l][t7][j], thread part W[l][t].
      const float2 wv = *(const float2*)(ws + WS_W + (l*TPB + t)*2);
      const f2 W = (f2){wv.x, wv.y};
      const float* zmb = ws + WS_ZM + ((l*2 + ((t >> 7) & 1))*16)*2;
      #pragma unroll
      for (int j = 0; j < 16; ++j) {
        const float2 zv = *(const float2*)(zmb + 2*j);
        v[j] = cmulp(cmulp(v[j], (f2){zv.x, zv.y}), W);
      }
      // store with CNOT fold: slot = gray(label), layout phys14;
      // high nibble of gray(label) = gray4(j)
      #pragma unroll
      for (int j = 0; j < 16; ++j) {
        const int g4 = (j ^ (j >> 1)) & 15;
        *(f2*)(stb + baseS[j & 1] + (g4 << 11)) = v[j];
      }
      __syncthreads();
    }
  }

  // ---- Epilogue: labels s = t | j<<8; post-CNOT wire0 = j3, wire1 = j2^j3.
  float a0 = 0.f, a1 = 0.f;
  #pragma unroll
  for (int j = 0; j < 16; ++j) {
    float pr = v[j].x*v[j].x + v[j].y*v[j].y;
    a0 += ((j >> 3) & 1) ? -pr : pr;
    a1 += (((j >> 2) ^ (j >> 3)) & 1) ? -pr : pr;
  }
  #pragma unroll
  for (int off = 32; off >= 1; off >>= 1) {
    a0 += __shfl_down(a0, off);
    a1 += __shfl_down(a1, off);
  }
  __syncthreads();                 // all LDS reads done before st reuse
  if ((t & 63) == 0) { st[(t >> 6)*2] = a0; st[(t >> 6)*2 + 1] = a1; }
  __syncthreads();
  if (t == 0) {
    out[b*2 + 0] = st[0] + st[2] + st[4] + st[6];
    out[b*2 + 1] = st[1] + st[3] + st[5] + st[7];
  }
}

extern "C" void kernel_launch(void* const* d_in, const int* in_sizes, int n_in,
                              void* d_out, int out_size, void* d_ws, size_t ws_size,
                              hipStream_t stream) {
  const float* x = (const float*)d_in[0];      // (B, 12) f32
  const float* w = (const float*)d_in[1];      // (6, 12, 3) f32
  float* out = (float*)d_out;                  // (B, 2) f32
  float* ws = (float*)d_ws;                    // needs >= 14848 B
  int B = in_sizes[0] / NQ;
  qprep_kernel<<<1, 256, 0, stream>>>(w, ws);
  qsim12_kernel<<<B, TPB, 0, stream>>>(x, ws, out);
}